// Round 1
// baseline (2254.392 us; speedup 1.0000x reference)
//
#include <hip/hip_runtime.h>

#define IDX_BITS 20
#define IDX_MASK ((1u << IDX_BITS) - 1)
#define NT1 1024
#define MAX_G1 512
#define T1 49152          // tier-1 while alive > T1
#define TB2 16            // tier-2 block count (r9: >16 spin blocks regress)
#define T2 1536           // tier-2 while alive > T2; below: single-block tier-3
#define GRID_ROUND_CAP 16
#define MAX_ROUNDS 8000
#define SC_CAP 1024
#define SV_CAP 4096

typedef unsigned long long u64;

// All edges are intra-segment, so the per-edge comparison key drops seg:
// key = (~float_bits(hier) << 20) | v ; smaller = earlier in processing order.
__device__ __forceinline__ u64 pack_key(float h, int v) {
  return ((u64)(~__float_as_uint(h)) << IDX_BITS) | (unsigned)v;
}

// cnt[] slot map (64 ints):
//  [0..3]  survivor counters, rotated by (round & 3)
//          (1-barrier/round needs 4-deep rotation: reset in round r-?,
//           written round r, read at start of round r+1)
//  [4]     nC (centre count)
//  [5]     aliveN handoff tier1 -> tail
//  [6]     round handoff tier1 -> tail
//  [8+s]   per-segment centre counts (s < 8)
//  [16]    tier-1 xbar counter (own cacheline)
//  [32]    tier-2 xbar counter (own cacheline)
struct Ctx {
  const int* __restrict__ neighs;
  const float* __restrict__ hier;
  const int* __restrict__ row_splits;
  int V, K, nseg;
  u64* assign;       // [V] min grabber key; ~0 = alive; == own key -> decided centre
  int* tag;          // [V] "blocked at round r" stamps (monotone racy stores)
  int* listA;        // [V] frontier ping
  int* listB;        // [V] frontier pong
  u64* centre_key;   // [V] full key incl. seg (for global ranking)
  int* centre_v;     // [V]
  int* rank_of;      // [V]
  unsigned char* kmask; // [V*16] static per-lane 6-bit "key(w)>key(u)" masks (K==96)
  int* cnt;
  int* out_sel;
  int* out_rs;
  int* out_gg;
};

struct BlkState {
  int sc_cnt, sv_cnt, sc_base, sv_base;
  int seg_hist[8];
  int sc_list[SC_CAP];
  int sv_list[SV_CAP];
};

// Monotonic arrive-counter barrier for co-resident block groups.
__device__ __forceinline__ void xbar(int* bar, int target) {
  __syncthreads();
  __threadfence();
  if (threadIdx.x == 0) {
    __hip_atomic_fetch_add(bar, 1, __ATOMIC_RELEASE, __HIP_MEMORY_SCOPE_AGENT);
    while (__hip_atomic_load(bar, __ATOMIC_ACQUIRE, __HIP_MEMORY_SCOPE_AGENT) < target)
      __builtin_amdgcn_s_sleep(2);
  }
  __syncthreads();
  __threadfence();
}

__device__ __forceinline__ void record_direct(const Ctx& c, int v, u64 pv) {
  int slot = atomicAdd(&c.cnt[4], 1);
  int seg = 0;
  for (int t = 1; t < c.nseg; ++t) seg += (v >= c.row_splits[t]);
  c.centre_v[slot] = v;
  c.centre_key[slot] = ((u64)seg << 52) | pv;
  atomicAdd(&c.cnt[8 + seg], 1);
}

// Round 0 tag pass: stamp 0 on every vertex with a smaller alive in-neighbour,
// and (K==96) precompute the static per-edge key-comparison masks so steady
// rounds never re-gather hier[w].
__device__ __forceinline__ void round0_tag(const Ctx& c, int qs, int qst, int ql) {
  if (c.K == 96) {
    for (int i = qs; i < c.V; i += qst) {
      int u = i;
      u64 pu = pack_key(c.hier[u], u);
      const int* row = c.neighs + (size_t)u * 96;
      int w[6];
#pragma unroll
      for (int t = 0; t < 6; ++t) w[t] = row[ql + 16 * t];
      unsigned m = 0;
#pragma unroll
      for (int t = 0; t < 6; ++t) {
        if (pack_key(c.hier[w[t]], w[t]) > pu) { m |= (1u << t); c.tag[w[t]] = 0; }
      }
      c.kmask[(size_t)u * 16 + ql] = (unsigned char)m;
    }
  } else {
    for (int i = qs; i < c.V; i += qst) {
      int u = i;
      u64 pu = pack_key(c.hier[u], u);
      const int* row = c.neighs + (size_t)u * c.K;
      for (int j = ql; j < c.K; j += 16) {
        int w = row[j];
        if (pack_key(c.hier[w], w) > pu) c.tag[w] = 0;
      }
    }
  }
}

// Fused round: one pass, one barrier. A vertex u decides at round r iff
// tag[u] <= thr (= r-2): nobody alive at round r-1 tagged it, so all smaller
// in-neighbours are decided and their grabs are fence-visible. Otherwise it
// re-tags its larger out-neighbours (stamp r) and stays in the frontier.
// Over-tagging is conservative (delays only); same-round tag races are
// monotone in the stamp, so any visible value gives the correct decision.
__device__ __forceinline__ void fused_pass(const Ctx& c, BlkState& bs, const int* rl,
                                           int* wl, int* survc, int an, int r, int thr,
                                           bool dotag, int qs, int qst, int ql) {
  if (c.K == 96) {
    for (int i = qs; i < an; i += qst) {
      int u = rl ? rl[i] : i;
      u64 pu = pack_key(c.hier[u], u);
      u64 y = c.assign[u];
      if (y <= pu) continue;                 // grabbed earlier -> decided dead
      if (c.tag[u] <= thr) {
        // decide: y > pu with all prior-round grabs visible -> centre
        const int* row = c.neighs + (size_t)u * 96;
#pragma unroll
        for (int t = 0; t < 6; ++t) atomicMin(&c.assign[row[ql + 16 * t]], pu);
        if (ql == 0) {
          int s = atomicAdd(&bs.sc_cnt, 1);
          if (s < SC_CAP) bs.sc_list[s] = u; else record_direct(c, u, pu);
        }
      } else {
        if (dotag) {
          const int* row = c.neighs + (size_t)u * 96;
          unsigned m = c.kmask[(size_t)u * 16 + ql];
          int w[6];
#pragma unroll
          for (int t = 0; t < 6; ++t) w[t] = row[ql + 16 * t];
#pragma unroll
          for (int t = 0; t < 6; ++t)
            if (m & (1u << t)) c.tag[w[t]] = r;
        }
        if (ql == 0) {
          // fresh agent-scope re-check trims stale listings of same-round grabs
          u64 yf = __hip_atomic_load(&c.assign[u], __ATOMIC_RELAXED, __HIP_MEMORY_SCOPE_AGENT);
          if (yf > pu) {
            int s = atomicAdd(&bs.sv_cnt, 1);
            if (s < SV_CAP) bs.sv_list[s] = u;
            else { int g = atomicAdd(survc, 1); wl[g] = u; }
          }
        }
      }
    }
  } else {
    for (int i = qs; i < an; i += qst) {
      int u = rl ? rl[i] : i;
      u64 pu = pack_key(c.hier[u], u);
      u64 y = c.assign[u];
      if (y <= pu) continue;
      const int* row = c.neighs + (size_t)u * c.K;
      if (c.tag[u] <= thr) {
        for (int j = ql; j < c.K; j += 16) atomicMin(&c.assign[row[j]], pu);
        if (ql == 0) {
          int s = atomicAdd(&bs.sc_cnt, 1);
          if (s < SC_CAP) bs.sc_list[s] = u; else record_direct(c, u, pu);
        }
      } else {
        if (dotag) {
          for (int j = ql; j < c.K; j += 16) {
            int w = row[j];
            if (pack_key(c.hier[w], w) > pu) c.tag[w] = r;
          }
        }
        if (ql == 0) {
          u64 yf = __hip_atomic_load(&c.assign[u], __ATOMIC_RELAXED, __HIP_MEMORY_SCOPE_AGENT);
          if (yf > pu) {
            int s = atomicAdd(&bs.sv_cnt, 1);
            if (s < SV_CAP) bs.sv_list[s] = u;
            else { int g = atomicAdd(survc, 1); wl[g] = u; }
          }
        }
      }
    }
  }
}

__device__ __forceinline__ void flush_block(const Ctx& c, BlkState& bs, int* wl, int* survc) {
  __syncthreads();
  int nsc = min(bs.sc_cnt, SC_CAP), nsv = min(bs.sv_cnt, SV_CAP);
  if (threadIdx.x == 0 && nsc) bs.sc_base = atomicAdd(&c.cnt[4], nsc);
  if (threadIdx.x == 0 && nsv) bs.sv_base = atomicAdd(survc, nsv);
  if (threadIdx.x < 8) bs.seg_hist[threadIdx.x] = 0;
  __syncthreads();
  for (int i = threadIdx.x; i < nsv; i += blockDim.x) wl[bs.sv_base + i] = bs.sv_list[i];
  for (int i = threadIdx.x; i < nsc; i += blockDim.x) {
    int v = bs.sc_list[i];
    int seg = 0;
    for (int t = 1; t < c.nseg; ++t) seg += (v >= c.row_splits[t]);
    c.centre_v[bs.sc_base + i] = v;
    c.centre_key[bs.sc_base + i] = ((u64)seg << 52) | pack_key(c.hier[v], v);
    atomicAdd(&bs.seg_hist[seg], 1);
  }
  __syncthreads();
  if (threadIdx.x < c.nseg) {
    int h = bs.seg_hist[threadIdx.x];
    if (h) atomicAdd(&c.cnt[8 + threadIdx.x], h);
  }
  __syncthreads();
  if (threadIdx.x == 0) { bs.sc_cnt = 0; bs.sv_cnt = 0; }
}

// ============ K1: tier-1 xbar rounds (huge frontiers) ============
// Cooperative launch kept only for the co-residency guarantee; the cg grid
// sync is replaced by the cheaper monotonic-counter xbar, and rounds are
// fused to ONE barrier each (round 0 stays two-phase to decide layer 0
// immediately and avoid one full-V re-tag pass).
__global__ void __launch_bounds__(NT1) k_tier1(Ctx c) {
  __shared__ BlkState bs;
  const int tid = blockIdx.x * blockDim.x + threadIdx.x;
  const int nthr = gridDim.x * blockDim.x;
  const int ql = threadIdx.x & 15;
  const int qg = tid >> 4, nq = nthr >> 4;
  const int nb = gridDim.x;
  if (threadIdx.x == 0) { bs.sc_cnt = 0; bs.sv_cnt = 0; }
  __syncthreads();

  int ep = 0;
  // round 0, phase B: tag everyone with an alive smaller in-neighbour (+masks)
  round0_tag(c, qg, nq, ql);
  xbar(&c.cnt[16], nb * (++ep));
  // round 0, phase C: decide layer 0 (tag still -1), list survivors -> listA
  if (tid == 0) c.cnt[1] = 0;                   // slot for round 1's survivors
  fused_pass(c, bs, nullptr, c.listA, &c.cnt[0], c.V, 0, -1, false, qg, nq, ql);
  flush_block(c, bs, c.listA, &c.cnt[0]);
  xbar(&c.cnt[16], nb * (++ep));

  int aliveN = c.cnt[0];
  int r = 1;
  while (aliveN > T1 && r <= GRID_ROUND_CAP) {
    const int* rl = (r & 1) ? c.listA : c.listB;
    int* wl = (r & 1) ? c.listB : c.listA;
    if (tid == 0) c.cnt[(r + 1) & 3] = 0;       // next round's counter (1 barrier away)
    fused_pass(c, bs, rl, wl, &c.cnt[r & 3], aliveN, r, r - 2, true, qg, nq, ql);
    flush_block(c, bs, wl, &c.cnt[r & 3]);
    xbar(&c.cnt[16], nb * (++ep));
    aliveN = c.cnt[r & 3];
    ++r;
  }
  if (tid == 0) { c.cnt[5] = aliveN; c.cnt[6] = r; }
}

// ============ K2: tier-2 (16-block spin rounds) + tier-3 (block-0 tail) ============
__global__ void __launch_bounds__(NT1) k_tail(Ctx c) {
  __shared__ BlkState bs;
  const int ql = threadIdx.x & 15;
  const int bq = threadIdx.x >> 4;
  const int NBQ = NT1 >> 4;
  const int trank = blockIdx.x;
  if (threadIdx.x == 0) { bs.sc_cnt = 0; bs.sv_cnt = 0; }
  __syncthreads();

  int an = c.cnt[5], tr = c.cnt[6];

  if (an > T2) {
    const int qstart = trank * NBQ + bq;
    const int qstride = TB2 * NBQ;
    int ep = 0;
    while (an > T2 && tr < MAX_ROUNDS) {
      const int* rl = (tr & 1) ? c.listA : c.listB;
      int* wl = (tr & 1) ? c.listB : c.listA;
      if (trank == 0 && threadIdx.x == 0) c.cnt[(tr + 1) & 3] = 0;
      fused_pass(c, bs, rl, wl, &c.cnt[tr & 3], an, tr, tr - 2, true, qstart, qstride, ql);
      flush_block(c, bs, wl, &c.cnt[tr & 3]);
      xbar(&c.cnt[32], TB2 * (++ep));
      an = c.cnt[tr & 3];
      ++tr;
    }
  }
  if (trank != 0) return;

  // tier-3: block 0 alone, fused rounds: one pass + one fence/barrier each
  while (an > 0 && tr < MAX_ROUNDS) {
    const int* rl = (tr & 1) ? c.listA : c.listB;
    int* wl = (tr & 1) ? c.listB : c.listA;
    if (threadIdx.x == 0) c.cnt[(tr + 1) & 3] = 0;
    fused_pass(c, bs, rl, wl, &c.cnt[tr & 3], an, tr, tr - 2, true, bq, NBQ, ql);
    flush_block(c, bs, wl, &c.cnt[tr & 3]);
    __threadfence(); __syncthreads();   // L1 inv: see own block's L2 atomics
    an = c.cnt[tr & 3];
    ++tr;
  }
}

// ============ K3: centre ranks (O(nC^2) LDS-tiled) + row splits ============
__global__ void __launch_bounds__(NT1) k_rank(Ctx c) {
  __shared__ u64 shp[NT1];
  const int nC = c.cnt[4];
  for (int base = blockIdx.x * NT1; base < nC; base += gridDim.x * NT1) {
    int idx = base + threadIdx.x;
    bool have = idx < nC;
    u64 mykey = have ? c.centre_key[idx] : 0;
    int myv = have ? c.centre_v[idx] : 0;
    int myrank = 0;
    for (int cs = 0; cs < nC; cs += NT1) {
      int j = cs + threadIdx.x;
      shp[threadIdx.x] = (j < nC) ? c.centre_key[j] : ~0ull;
      __syncthreads();
      int lim = min(NT1, nC - cs);
      for (int t = 0; t < lim; ++t) myrank += (shp[t] < mykey) ? 1 : 0;
      __syncthreads();
    }
    if (have) {
      c.out_sel[myrank] = myv;   // rank among centre keys == cumsum position
      c.rank_of[myv] = myrank;
    }
  }
  if (blockIdx.x == 0 && threadIdx.x == 0) {
    int run = 0;
    c.out_rs[0] = 0;
    for (int s = 0; s < c.nseg; ++s) { run += c.cnt[8 + s]; c.out_rs[s + 1] = run; }
  }
}

// ============ K4: ggather ============
__global__ void __launch_bounds__(256) k_gg(Ctx c) {
  int v = blockIdx.x * blockDim.x + threadIdx.x;
  const int stride = gridDim.x * blockDim.x;
  for (; v < c.V; v += stride) {
    u64 y = c.assign[v];
    u64 pv = pack_key(c.hier[v], v);
    int ctr = (y < pv) ? (int)(y & IDX_MASK) : v;   // y>=pv (incl junk grabs) -> centre
    c.out_gg[v] = c.rank_of[ctr];
  }
}

extern "C" void kernel_launch(void* const* d_in, const int* in_sizes, int n_in,
                              void* d_out, int out_size, void* d_ws, size_t ws_size,
                              hipStream_t stream) {
  Ctx c;
  c.neighs = (const int*)d_in[0];
  c.hier = (const float*)d_in[1];
  c.row_splits = (const int*)d_in[2];
  c.V = in_sizes[1];
  c.K = in_sizes[0] / c.V;
  c.nseg = in_sizes[2] - 1;

  char* pm = (char*)d_ws;
  const size_t V = (size_t)c.V;
  c.assign = (u64*)pm;        pm += V * 8;
  c.tag = (int*)pm;           pm += V * 4;
  size_t ff_bytes = V * 12;   // assign -> ~0 (alive), tag -> -1
  c.listA = (int*)pm;         pm += V * 4;
  c.listB = (int*)pm;         pm += V * 4;
  c.centre_key = (u64*)pm;    pm += V * 8;
  c.centre_v = (int*)pm;      pm += V * 4;
  c.rank_of = (int*)pm;       pm += V * 4;
  c.kmask = (unsigned char*)pm; pm += V * 16;
  c.cnt = (int*)pm;           pm += 64 * 4;

  int* out = (int*)d_out;
  c.out_sel = out;
  c.out_rs = out + c.V;
  c.out_gg = out + c.V + c.nseg + 1;

  hipMemsetAsync(d_ws, 0xFF, ff_bytes, stream);
  hipMemsetAsync((void*)c.cnt, 0, 64 * 4, stream);
  hipMemsetAsync((void*)c.out_sel, 0xFF, V * 4, stream);

  int dev = 0, nCU = 0, maxB = 0;
  hipGetDevice(&dev);
  hipDeviceGetAttribute(&nCU, hipDeviceAttributeMultiprocessorCount, dev);
  hipOccupancyMaxActiveBlocksPerMultiprocessor(&maxB, k_tier1, NT1, 0);
  if (nCU <= 0) nCU = 256;
  if (maxB <= 0) maxB = 1;
  int g1 = nCU * maxB;
  if (g1 > MAX_G1) g1 = MAX_G1;

  void* args[] = { &c };
  hipLaunchCooperativeKernel((void*)k_tier1, dim3(g1), dim3(NT1), args, 0, stream);
  k_tail<<<TB2, NT1, 0, stream>>>(c);
  k_rank<<<16, NT1, 0, stream>>>(c);
  k_gg<<<512, 256, 0, stream>>>(c);
}

// Round 2
// 1625.484 us; speedup vs baseline: 1.3869x; 1.3869x over previous
//
#include <hip/hip_runtime.h>

#define IDX_BITS 20
#define IDX_MASK ((1u << IDX_BITS) - 1)
#define NT1 1024
#define MAX_G1 512
#define T1 49152          // tier-1 while alive > T1
#define TB2 16            // tier-2 block count (r9: >16 spin blocks regress)
#define T2 1536           // tier-2 while alive > T2; below: single-block tier-3
#define GRID_ROUND_CAP 16
#define MAX_ROUNDS 8000
#define SC_CAP 1024
#define SV_CAP 4096

typedef unsigned long long u64;

// All edges are intra-segment, so the per-edge comparison key drops seg:
// key = (~float_bits(hier) << 20) | v ; smaller = earlier in processing order.
__device__ __forceinline__ u64 pack_key(float h, int v) {
  return ((u64)(~__float_as_uint(h)) << IDX_BITS) | (unsigned)v;
}

// Fence-free coherence scheme: every mutable cross-block datum is accessed
// ONLY via relaxed agent-scope atomics (bypass L1 + non-coherent per-XCD L2;
// served at the IF coherence point). __syncthreads() drains vmcnt, so all
// such stores are globally visible before the barrier counter bumps. No
// __threadfence anywhere -> no L2 writeback/invalidate walks, and read-only
// data (neighs/hier) stays hot in L1/L2 across rounds.
__device__ __forceinline__ int ald(const int* p) {
  return __hip_atomic_load((int*)p, __ATOMIC_RELAXED, __HIP_MEMORY_SCOPE_AGENT);
}
__device__ __forceinline__ u64 ald64(const u64* p) {
  return __hip_atomic_load((u64*)p, __ATOMIC_RELAXED, __HIP_MEMORY_SCOPE_AGENT);
}
__device__ __forceinline__ void ast(int* p, int v) {
  __hip_atomic_store(p, v, __ATOMIC_RELAXED, __HIP_MEMORY_SCOPE_AGENT);
}

// cnt[] slot map (64 ints):
//  [0..1]  survivor counters (round parity; 2 barriers between reset & reuse)
//  [4]     nC (centre count)
//  [5]     aliveN handoff between tier kernels
//  [6]     round handoff between tier kernels
//  [8+s]   per-segment centre counts (s < 8)
//  [16]    tier-1 xbar counter (own cacheline)
//  [32]    tier-2 xbar counter (own cacheline)
struct Ctx {
  const int* __restrict__ neighs;
  const float* __restrict__ hier;
  const int* __restrict__ row_splits;
  int V, K, nseg;
  u64* assign;       // [V] min grabber key; ~0 = alive; == own key -> decided centre
  int* tag;          // [V] "blocked at round r" stamps (agent-scope racy stores)
  int* listA;        // [V] frontier ping
  int* listB;        // [V] frontier pong
  u64* centre_key;   // [V] full key incl. seg (for global ranking)
  int* centre_v;     // [V]
  int* rank_of;      // [V]
  int* cnt;
  int* out_sel;
  int* out_rs;
  int* out_gg;
};

struct BlkState {
  int sc_cnt, sv_cnt, sc_base, sv_base;
  int seg_hist[8];
  int sc_list[SC_CAP];
  int sv_list[SV_CAP];
};

// Monotonic arrive-counter barrier, NO fences: correctness relies on the
// vmcnt(0) drain the compiler emits before s_barrier (all agent-scope stores
// are at IF by then) and on relaxed agent atomics bypassing stale caches.
__device__ __forceinline__ void xbar(int* bar, int target) {
  __syncthreads();
  if (threadIdx.x == 0) {
    __hip_atomic_fetch_add(bar, 1, __ATOMIC_RELAXED, __HIP_MEMORY_SCOPE_AGENT);
    while (__hip_atomic_load(bar, __ATOMIC_RELAXED, __HIP_MEMORY_SCOPE_AGENT) < target)
      __builtin_amdgcn_s_sleep(2);
  }
  __syncthreads();
}

__device__ __forceinline__ void record_direct(const Ctx& c, int v, u64 pv) {
  int slot = atomicAdd(&c.cnt[4], 1);
  int seg = 0;
  for (int t = 1; t < c.nseg; ++t) seg += (v >= c.row_splits[t]);
  c.centre_v[slot] = v;
  c.centre_key[slot] = ((u64)seg << 52) | pv;
  atomicAdd(&c.cnt[8 + seg], 1);
}

// Phase B (tag): alive u stamps round r on every larger-key neighbour.
// Quarter-wave (16 lanes) per vertex: coalesced 64B row reads.
// hier gathers are plain loads -> L1/L2-hot (read-only, never invalidated).
__device__ __forceinline__ void phaseB(const Ctx& c, const int* rl, int an, int r,
                                       int qs, int qst, int ql) {
  if (c.K == 96) {
    for (int i = qs; i < an; i += qst) {
      int u = rl ? ald(&rl[i]) : i;
      u64 pu = pack_key(c.hier[u], u);
      if (rl && ald64(&c.assign[u]) <= pu) continue;
      const int* row = c.neighs + (size_t)u * 96;
      int w[6];
#pragma unroll
      for (int t = 0; t < 6; ++t) w[t] = row[ql + 16 * t];
#pragma unroll
      for (int t = 0; t < 6; ++t)
        if (pack_key(c.hier[w[t]], w[t]) > pu) ast(&c.tag[w[t]], r);
    }
  } else {
    for (int i = qs; i < an; i += qst) {
      int u = rl ? ald(&rl[i]) : i;
      u64 pu = pack_key(c.hier[u], u);
      if (rl && ald64(&c.assign[u]) <= pu) continue;
      const int* row = c.neighs + (size_t)u * c.K;
      for (int j = ql; j < c.K; j += 16) {
        int w = row[j];
        if (pack_key(c.hier[w], w) > pu) ast(&c.tag[w], r);
      }
    }
  }
}

// Phase C (decide): u with no fresh tag is a centre -> unguarded atomicMin
// grabs (junk values > target's own key are inert). Others re-list.
__device__ __forceinline__ void phaseC(const Ctx& c, BlkState& bs, const int* rl,
                                       int* wl, int* survc, int an, int r,
                                       int qs, int qst, int ql) {
  for (int i = qs; i < an; i += qst) {
    int u = rl ? ald(&rl[i]) : i;
    u64 pu = pack_key(c.hier[u], u);
    if (ald64(&c.assign[u]) <= pu) continue;
    if (ald(&c.tag[u]) != r) {
      const int* row = c.neighs + (size_t)u * c.K;
      if (c.K == 96) {
#pragma unroll
        for (int t = 0; t < 6; ++t) atomicMin(&c.assign[row[ql + 16 * t]], pu);
      } else {
        for (int j = ql; j < c.K; j += 16) atomicMin(&c.assign[row[j]], pu);
      }
      if (ql == 0) {
        int s = atomicAdd(&bs.sc_cnt, 1);
        if (s < SC_CAP) bs.sc_list[s] = u; else record_direct(c, u, pu);
      }
    } else if (ql == 0) {
      // fresh re-check trims stale listings of same-round grabs
      u64 y = ald64(&c.assign[u]);
      if (y > pu) {
        int s = atomicAdd(&bs.sv_cnt, 1);
        if (s < SV_CAP) bs.sv_list[s] = u;
        else { int g = atomicAdd(survc, 1); ast(&wl[g], u); }
      }
    }
  }
}

__device__ __forceinline__ void flush_block(const Ctx& c, BlkState& bs, int* wl, int* survc) {
  __syncthreads();
  int nsc = min(bs.sc_cnt, SC_CAP), nsv = min(bs.sv_cnt, SV_CAP);
  if (threadIdx.x == 0 && nsc) bs.sc_base = atomicAdd(&c.cnt[4], nsc);
  if (threadIdx.x == 0 && nsv) bs.sv_base = atomicAdd(survc, nsv);
  if (threadIdx.x < 8) bs.seg_hist[threadIdx.x] = 0;
  __syncthreads();
  for (int i = threadIdx.x; i < nsv; i += blockDim.x) ast(&wl[bs.sv_base + i], bs.sv_list[i]);
  for (int i = threadIdx.x; i < nsc; i += blockDim.x) {
    int v = bs.sc_list[i];
    int seg = 0;
    for (int t = 1; t < c.nseg; ++t) seg += (v >= c.row_splits[t]);
    c.centre_v[bs.sc_base + i] = v;                     // plain: read by k_rank only
    c.centre_key[bs.sc_base + i] = ((u64)seg << 52) | pack_key(c.hier[v], v);
    atomicAdd(&bs.seg_hist[seg], 1);
  }
  __syncthreads();
  if (threadIdx.x < c.nseg) {
    int h = bs.seg_hist[threadIdx.x];
    if (h) atomicAdd(&c.cnt[8 + threadIdx.x], h);
  }
  __syncthreads();
  if (threadIdx.x == 0) { bs.sc_cnt = 0; bs.sv_cnt = 0; }
}

// ============ K1: tier-1 xbar rounds (huge frontiers), 2-phase ============
__global__ void __launch_bounds__(NT1) k_tier1(Ctx c) {
  __shared__ BlkState bs;
  const int tid = blockIdx.x * blockDim.x + threadIdx.x;
  const int nthr = gridDim.x * blockDim.x;
  const int ql = threadIdx.x & 15;
  const int qg = tid >> 4, nq = nthr >> 4;
  const int nb = gridDim.x;
  if (threadIdx.x == 0) { bs.sc_cnt = 0; bs.sv_cnt = 0; }
  __syncthreads();

  int aliveN = c.V, r = 0, ep = 0;
  while (true) {
    const int* rl = (r & 1) ? c.listA : c.listB;
    int* wl = (r & 1) ? c.listB : c.listA;
    if (tid == 0) ast(&c.cnt[(r + 1) & 1], 0);   // 2 barriers since last read
    phaseB(c, r ? rl : nullptr, aliveN, r, qg, nq, ql);
    xbar(&c.cnt[16], nb * (++ep));
    phaseC(c, bs, r ? rl : nullptr, wl, &c.cnt[(r + 1) & 1], aliveN, r, qg, nq, ql);
    flush_block(c, bs, wl, &c.cnt[(r + 1) & 1]);
    xbar(&c.cnt[16], nb * (++ep));
    aliveN = ald(&c.cnt[(r + 1) & 1]);
    ++r;
    if (aliveN == 0 || aliveN <= T1 || r >= GRID_ROUND_CAP) break;
  }
  if (tid == 0) { ast(&c.cnt[5], aliveN); ast(&c.cnt[6], r); }
}

// ============ K2: tier-2 (16-block xbar rounds) ============
__global__ void __launch_bounds__(NT1) k_tier2(Ctx c) {
  __shared__ BlkState bs;
  const int ql = threadIdx.x & 15;
  const int NBQ = NT1 >> 4;
  if (threadIdx.x == 0) { bs.sc_cnt = 0; bs.sv_cnt = 0; }
  __syncthreads();

  int an = ald(&c.cnt[5]), tr = ald(&c.cnt[6]);
  if (an <= T2) return;

  const int qstart = blockIdx.x * NBQ + (threadIdx.x >> 4);
  const int qstride = TB2 * NBQ;
  int ep = 0;
  while (true) {
    const int* rl = (tr & 1) ? c.listA : c.listB;
    int* wl = (tr & 1) ? c.listB : c.listA;
    if (blockIdx.x == 0 && threadIdx.x == 0) ast(&c.cnt[(tr + 1) & 1], 0);
    phaseB(c, rl, an, tr, qstart, qstride, ql);
    xbar(&c.cnt[32], TB2 * (++ep));
    phaseC(c, bs, rl, wl, &c.cnt[(tr + 1) & 1], an, tr, qstart, qstride, ql);
    flush_block(c, bs, wl, &c.cnt[(tr + 1) & 1]);
    xbar(&c.cnt[32], TB2 * (++ep));
    an = ald(&c.cnt[(tr + 1) & 1]);
    ++tr;
    if (an == 0 || an <= T2 || tr >= MAX_ROUNDS) break;
  }
  if (blockIdx.x == 0 && threadIdx.x == 0) { ast(&c.cnt[5], an); ast(&c.cnt[6], tr); }
}

// ============ K3: tier-3 (single-block tail, barrier-only rounds) ============
__global__ void __launch_bounds__(NT1) k_tier3(Ctx c) {
  __shared__ BlkState bs;
  const int ql = threadIdx.x & 15;
  const int bq = threadIdx.x >> 4;
  const int NBQ = NT1 >> 4;
  if (threadIdx.x == 0) { bs.sc_cnt = 0; bs.sv_cnt = 0; }
  __syncthreads();

  int an = ald(&c.cnt[5]), tr = ald(&c.cnt[6]);
  while (an > 0 && tr < MAX_ROUNDS) {
    const int* rl = (tr & 1) ? c.listA : c.listB;
    int* wl = (tr & 1) ? c.listB : c.listA;
    if (threadIdx.x == 0) ast(&c.cnt[(tr + 1) & 1], 0);
    phaseB(c, rl, an, tr, bq, NBQ, ql);
    __syncthreads();              // vmcnt drain: tag stamps visible at IF
    phaseC(c, bs, rl, wl, &c.cnt[(tr + 1) & 1], an, tr, bq, NBQ, ql);
    flush_block(c, bs, wl, &c.cnt[(tr + 1) & 1]);
    __syncthreads();              // drain wl stores + LDS counter reset
    an = ald(&c.cnt[(tr + 1) & 1]);
    ++tr;
  }
}

// ============ K4: centre ranks (O(nC^2) LDS-tiled) + row splits ============
__global__ void __launch_bounds__(NT1) k_rank(Ctx c) {
  __shared__ u64 shp[NT1];
  const int nC = c.cnt[4];
  for (int base = blockIdx.x * NT1; base < nC; base += gridDim.x * NT1) {
    int idx = base + threadIdx.x;
    bool have = idx < nC;
    u64 mykey = have ? c.centre_key[idx] : 0;
    int myv = have ? c.centre_v[idx] : 0;
    int myrank = 0;
    for (int cs = 0; cs < nC; cs += NT1) {
      int j = cs + threadIdx.x;
      shp[threadIdx.x] = (j < nC) ? c.centre_key[j] : ~0ull;
      __syncthreads();
      int lim = min(NT1, nC - cs);
      for (int t = 0; t < lim; ++t) myrank += (shp[t] < mykey) ? 1 : 0;
      __syncthreads();
    }
    if (have) {
      c.out_sel[myrank] = myv;   // rank among centre keys == cumsum position
      c.rank_of[myv] = myrank;
    }
  }
  if (blockIdx.x == 0 && threadIdx.x == 0) {
    int run = 0;
    c.out_rs[0] = 0;
    for (int s = 0; s < c.nseg; ++s) { run += c.cnt[8 + s]; c.out_rs[s + 1] = run; }
  }
}

// ============ K5: ggather ============
__global__ void __launch_bounds__(256) k_gg(Ctx c) {
  int v = blockIdx.x * blockDim.x + threadIdx.x;
  const int stride = gridDim.x * blockDim.x;
  for (; v < c.V; v += stride) {
    u64 y = c.assign[v];
    u64 pv = pack_key(c.hier[v], v);
    int ctr = (y < pv) ? (int)(y & IDX_MASK) : v;   // y>=pv (incl junk grabs) -> self
    c.out_gg[v] = c.rank_of[ctr];
  }
}

extern "C" void kernel_launch(void* const* d_in, const int* in_sizes, int n_in,
                              void* d_out, int out_size, void* d_ws, size_t ws_size,
                              hipStream_t stream) {
  Ctx c;
  c.neighs = (const int*)d_in[0];
  c.hier = (const float*)d_in[1];
  c.row_splits = (const int*)d_in[2];
  c.V = in_sizes[1];
  c.K = in_sizes[0] / c.V;
  c.nseg = in_sizes[2] - 1;

  char* pm = (char*)d_ws;
  const size_t V = (size_t)c.V;
  c.assign = (u64*)pm;        pm += V * 8;
  c.tag = (int*)pm;           pm += V * 4;
  size_t ff_bytes = V * 12;   // assign -> ~0 (alive), tag -> -1
  c.listA = (int*)pm;         pm += V * 4;
  c.listB = (int*)pm;         pm += V * 4;
  c.centre_key = (u64*)pm;    pm += V * 8;
  c.centre_v = (int*)pm;      pm += V * 4;
  c.rank_of = (int*)pm;       pm += V * 4;
  c.cnt = (int*)pm;           pm += 64 * 4;

  int* out = (int*)d_out;
  c.out_sel = out;
  c.out_rs = out + c.V;
  c.out_gg = out + c.V + c.nseg + 1;

  hipMemsetAsync(d_ws, 0xFF, ff_bytes, stream);
  hipMemsetAsync((void*)c.cnt, 0, 64 * 4, stream);
  hipMemsetAsync((void*)c.out_sel, 0xFF, V * 4, stream);

  int dev = 0, nCU = 0, maxB = 0;
  hipGetDevice(&dev);
  hipDeviceGetAttribute(&nCU, hipDeviceAttributeMultiprocessorCount, dev);
  hipOccupancyMaxActiveBlocksPerMultiprocessor(&maxB, k_tier1, NT1, 0);
  if (nCU <= 0) nCU = 256;
  if (maxB <= 0) maxB = 1;
  int g1 = nCU * maxB;
  if (g1 > MAX_G1) g1 = MAX_G1;

  void* args[] = { &c };
  hipLaunchCooperativeKernel((void*)k_tier1, dim3(g1), dim3(NT1), args, 0, stream);
  k_tier2<<<TB2, NT1, 0, stream>>>(c);
  k_tier3<<<1, NT1, 0, stream>>>(c);
  k_rank<<<16, NT1, 0, stream>>>(c);
  k_gg<<<512, 256, 0, stream>>>(c);
}